// Round 3
// baseline (3860.970 us; speedup 1.0000x reference)
//
#include <hip/hip_runtime.h>

#define D_MODEL 768
#define D_INNER 1536
#define SEQ 1024
#define DT_RANK 48
#define D_STATE 16
#define VOCAB 50280

typedef __attribute__((ext_vector_type(8))) short short8;
typedef __attribute__((ext_vector_type(4))) float float4v;

static __device__ __forceinline__ unsigned short f2bf(float f) {
    unsigned u = __builtin_bit_cast(unsigned, f);
    u += 0x7fffu + ((u >> 16) & 1u);   // RNE
    return (unsigned short)(u >> 16);
}

// ---------------------------------------------------------------- embed
__global__ __launch_bounds__(256) void embed_kernel(
    const int* __restrict__ ids, const float* __restrict__ emb,
    float* __restrict__ h)
{
    int d = blockIdx.x * 256 + threadIdx.x;   // < 768
    int l = blockIdx.y;
    h[l * D_MODEL + d] = emb[(size_t)ids[l] * D_MODEL + d];
}

// ---------------------------------------------------------------- layernorm (768 cols)
__global__ __launch_bounds__(256) void ln_kernel(
    const float* __restrict__ in, const float* __restrict__ w,
    const float* __restrict__ b, float* __restrict__ out)
{
    int row = blockIdx.x, tid = threadIdx.x;
    const float* p = in + (size_t)row * D_MODEL;
    float x0 = p[tid], x1 = p[tid + 256], x2 = p[tid + 512];
    float s = x0 + x1 + x2;
    float s2 = x0 * x0 + x1 * x1 + x2 * x2;
    #pragma unroll
    for (int o = 1; o < 64; o <<= 1) {
        s  += __shfl_xor(s, o);
        s2 += __shfl_xor(s2, o);
    }
    __shared__ float rs[4], rs2[4], mv[2];
    int wv = tid >> 6, lane = tid & 63;
    if (lane == 0) { rs[wv] = s; rs2[wv] = s2; }
    __syncthreads();
    if (tid == 0) {
        float S = rs[0] + rs[1] + rs[2] + rs[3];
        float S2 = rs2[0] + rs2[1] + rs2[2] + rs2[3];
        float mu = S / (float)D_MODEL;
        float var = S2 / (float)D_MODEL - mu * mu;
        mv[0] = mu; mv[1] = rsqrtf(fmaxf(var, 0.f) + 1e-5f);
    }
    __syncthreads();
    float mu = mv[0], rstd = mv[1];
    float* q = out + (size_t)row * D_MODEL;
    q[tid]       = (x0 - mu) * rstd * w[tid]       + b[tid];
    q[tid + 256] = (x1 - mu) * rstd * w[tid + 256] + b[tid + 256];
    q[tid + 512] = (x2 - mu) * rstd * w[tid + 512] + b[tid + 512];
}

// ---------------------------------------------------------------- causal depthwise conv4 + silu
__global__ __launch_bounds__(256) void conv_silu_kernel(
    const float* __restrict__ xz, const float* __restrict__ cw,
    const float* __restrict__ cb, float* __restrict__ xc)
{
    int d = blockIdx.x * 256 + threadIdx.x;   // < 1536
    int l = blockIdx.y;
    float acc = cb[d];
    #pragma unroll
    for (int j = 0; j < 4; ++j) {
        int ll = l - 3 + j;
        if (ll >= 0)
            acc += xz[(size_t)ll * (2 * D_INNER) + d] * cw[d * 4 + j];
    }
    float sig = 1.f / (1.f + __expf(-acc));
    xc[(size_t)l * D_INNER + d] = acc * sig;
}

// ---------------------------------------------------------------- dt_proj: softplus(dt_in @ W^T + b)
__global__ __launch_bounds__(256) void dtproj_kernel(
    const float* __restrict__ xdbl, const float* __restrict__ w,
    const float* __restrict__ b, float* __restrict__ dtb)
{
    int l = blockIdx.y;
    int d = blockIdx.x * 256 + threadIdx.x;   // < 1536
    __shared__ float xr[DT_RANK];
    if (threadIdx.x < DT_RANK) xr[threadIdx.x] = xdbl[(size_t)l * 80 + threadIdx.x];
    __syncthreads();
    const float4v* wp = (const float4v*)(w + (size_t)d * DT_RANK);
    float acc = b[d];
    #pragma unroll
    for (int i = 0; i < DT_RANK / 4; ++i) {
        float4v ww = wp[i];
        #pragma unroll
        for (int j = 0; j < 4; ++j)
            acc += xr[i * 4 + j] * ww[j];
    }
    float sp = (acc > 20.f) ? acc : log1pf(__expf(acc));
    dtb[(size_t)l * D_INNER + d] = sp;
}

// ---------------------------------------------------------------- selective scan
// one lane per (channel d, state n). 16 lanes per channel, 16 channels per block.
__global__ __launch_bounds__(256) void scan_kernel(
    const float* __restrict__ xc,    // (L, DI) conv+silu output
    const float* __restrict__ dtb,   // (L, DI) softplus(dt)
    const float* __restrict__ xdbl,  // (L, 80): [..,48:64]=B, [..,64:80]=C
    const float* __restrict__ xz,    // (L, 3072): z = cols 1536..
    const float* __restrict__ A_log, // (DI, 16)
    const float* __restrict__ Dw,    // (DI)
    float* __restrict__ y)           // (L, DI)
{
    int tid = threadIdx.x;
    int n = tid & 15;
    int d = blockIdx.x * 16 + (tid >> 4);
    float Av = -__expf(A_log[d * D_STATE + n]);
    float Dv = Dw[d];
    float h = 0.f;
    float dt_c = dtb[d];
    float x_c  = xc[d];
    float B_c  = xdbl[DT_RANK + n];
    float C_c  = xdbl[DT_RANK + D_STATE + n];
    for (int l = 0; l < SEQ; ++l) {
        float dt_n = 0.f, x_n = 0.f, B_n = 0.f, C_n = 0.f;
        if (l < SEQ - 1) {  // prefetch next step
            size_t o = (size_t)(l + 1);
            dt_n = dtb[o * D_INNER + d];
            x_n  = xc[o * D_INNER + d];
            B_n  = xdbl[o * 80 + DT_RANK + n];
            C_n  = xdbl[o * 80 + DT_RANK + D_STATE + n];
        }
        float dA = __expf(dt_c * Av);
        h = dA * h + (dt_c * x_c) * B_c;
        float p = h * C_c;
        p += __shfl_xor(p, 1);
        p += __shfl_xor(p, 2);
        p += __shfl_xor(p, 4);
        p += __shfl_xor(p, 8);
        if (n == 0) {
            float zv = xz[(size_t)l * (2 * D_INNER) + D_INNER + d];
            float sig = 1.f / (1.f + __expf(-zv));
            y[(size_t)l * D_INNER + d] = (p + x_c * Dv) * (zv * sig);
        }
        dt_c = dt_n; x_c = x_n; B_c = B_n; C_c = C_n;
    }
}

// ---------------------------------------------------------------- GEMM  C = A(MxK,f32) * B(NxK,f32)^T, bf16 MFMA compute
// Requires M%128==0, K%32==0. 128x128 tile, 4 waves, 4x4 of 16x16x32 bf16 MFMA.
#define BM 128
#define BN 128
#define BK 32

enum { MODE_PLAIN = 0, MODE_ADD = 1 };

template <int MODE>
__global__ __launch_bounds__(256) void gemm_bt(
    const float* __restrict__ A, const float* __restrict__ B,
    float* Cout, int M, int N, int K, int lda,
    const float* addend)
{
    __shared__ unsigned short As[BM][BK + 8];
    __shared__ unsigned short Bs[BN][BK + 8];

    int tid = threadIdx.x;
    int lane = tid & 63, wv = tid >> 6;
    int wm = (wv >> 1) * 64, wn = (wv & 1) * 64;
    int lm = lane & 15, quad = lane >> 4;
    int m0 = blockIdx.x * BM, n0 = blockIdx.y * BN;

    int r = tid >> 1;            // staging row 0..127
    int ch = (tid & 1) * 16;     // staging col offset 0/16

    float4v acc[4][4] = {};

    for (int k0 = 0; k0 < K; k0 += BK) {
        // ---- stage A (f32 -> bf16), always in-bounds: M%128==0, K%32==0
        {
            const float4v* ap4 = (const float4v*)(A + (size_t)(m0 + r) * lda + k0 + ch);
            float4v f0 = ap4[0], f1 = ap4[1], f2 = ap4[2], f3 = ap4[3];
            short8 t0, t1;
            #pragma unroll
            for (int j = 0; j < 4; ++j) {
                t0[j]     = (short)f2bf(f0[j]);
                t0[j + 4] = (short)f2bf(f1[j]);
                t1[j]     = (short)f2bf(f2[j]);
                t1[j + 4] = (short)f2bf(f3[j]);
            }
            *(short8*)&As[r][ch]     = t0;
            *(short8*)&As[r][ch + 8] = t1;
        }
        // ---- stage B (f32 -> bf16), row guard only
        {
            short8 u0, u1;
            if ((n0 + r) < N) {
                const float4v* bp4 = (const float4v*)(B + (size_t)(n0 + r) * K + k0 + ch);
                float4v g0 = bp4[0], g1 = bp4[1], g2 = bp4[2], g3 = bp4[3];
                #pragma unroll
                for (int j = 0; j < 4; ++j) {
                    u0[j]     = (short)f2bf(g0[j]);
                    u0[j + 4] = (short)f2bf(g1[j]);
                    u1[j]     = (short)f2bf(g2[j]);
                    u1[j + 4] = (short)f2bf(g3[j]);
                }
            } else {
                u0 = (short8)(short)0;
                u1 = (short8)(short)0;
            }
            *(short8*)&Bs[r][ch]     = u0;
            *(short8*)&Bs[r][ch + 8] = u1;
        }
        __syncthreads();

        short8 af[4], bfr[4];
        #pragma unroll
        for (int i = 0; i < 4; ++i)
            af[i] = *(const short8*)&As[wm + i * 16 + lm][quad * 8];
        #pragma unroll
        for (int i = 0; i < 4; ++i)
            bfr[i] = *(const short8*)&Bs[wn + i * 16 + lm][quad * 8];

        #pragma unroll
        for (int mi = 0; mi < 4; ++mi)
            #pragma unroll
            for (int ni = 0; ni < 4; ++ni)
                acc[mi][ni] = __builtin_amdgcn_mfma_f32_16x16x32_bf16(
                    af[mi], bfr[ni], acc[mi][ni], 0, 0, 0);

        __syncthreads();
    }

    // ---- epilogue: C row = quad*4+e, col = lm  (verified C/D layout)
    #pragma unroll
    for (int mi = 0; mi < 4; ++mi) {
        #pragma unroll
        for (int ni = 0; ni < 4; ++ni) {
            int m = m0 + wm + mi * 16 + quad * 4;
            int n = n0 + wn + ni * 16 + lm;
            if (n >= N) continue;
            #pragma unroll
            for (int e = 0; e < 4; ++e) {
                float v = acc[mi][ni][e];
                size_t off = (size_t)(m + e) * N + n;
                if (MODE == MODE_PLAIN) {
                    Cout[off] = v;
                } else {
                    Cout[off] = v + addend[off];
                }
            }
        }
    }
}

// ---------------------------------------------------------------- launch
extern "C" void kernel_launch(void* const* d_in, const int* in_sizes, int n_in,
                              void* d_out, int out_size, void* d_ws, size_t ws_size,
                              hipStream_t stream)
{
    const int*   ids   = (const int*)d_in[0];
    const float* emb   = (const float*)d_in[1];
    const float* ln_w  = (const float*)d_in[2];
    const float* ln_b  = (const float*)d_in[3];
    const float* inw   = (const float*)d_in[4];
    const float* cw    = (const float*)d_in[5];
    const float* cb    = (const float*)d_in[6];
    const float* xpw   = (const float*)d_in[7];
    const float* dtpw  = (const float*)d_in[8];
    const float* dtpb  = (const float*)d_in[9];
    const float* alog  = (const float*)d_in[10];
    const float* Dw    = (const float*)d_in[11];
    const float* outw  = (const float*)d_in[12];
    const float* lnfw  = (const float*)d_in[13];
    const float* lnfb  = (const float*)d_in[14];

    float* ws    = (float*)d_ws;
    float* ha    = ws;                           // 1024*768
    float* hb    = ha    + SEQ * D_MODEL;        // 1024*768
    float* hn    = hb    + SEQ * D_MODEL;        // 1024*768
    float* xz    = hn    + SEQ * D_MODEL;        // 1024*3072
    float* xconv = xz    + SEQ * 2 * D_INNER;    // 1024*1536
    float* xdbl  = xconv + SEQ * D_INNER;        // 1024*80
    float* dtb   = xdbl  + SEQ * 80;             // 1024*1536
    float* y     = dtb   + SEQ * D_INNER;        // 1024*1536

    embed_kernel<<<dim3(3, SEQ), 256, 0, stream>>>(ids, emb, ha);

    float* hcur = ha;
    float* hnxt = hb;
    for (int i = 0; i < 4; ++i) {
        ln_kernel<<<SEQ, 256, 0, stream>>>(hcur, ln_w + i * D_MODEL, ln_b + i * D_MODEL, hn);

        gemm_bt<MODE_PLAIN><<<dim3(8, 24), 256, 0, stream>>>(
            hn, inw + (size_t)i * 2 * D_INNER * D_MODEL, xz,
            SEQ, 2 * D_INNER, D_MODEL, D_MODEL, nullptr);

        conv_silu_kernel<<<dim3(6, SEQ), 256, 0, stream>>>(
            xz, cw + (size_t)i * D_INNER * 4, cb + (size_t)i * D_INNER, xconv);

        gemm_bt<MODE_PLAIN><<<dim3(8, 1), 256, 0, stream>>>(
            xconv, xpw + (size_t)i * 80 * D_INNER, xdbl,
            SEQ, 80, D_INNER, D_INNER, nullptr);

        dtproj_kernel<<<dim3(6, SEQ), 256, 0, stream>>>(
            xdbl, dtpw + (size_t)i * D_INNER * DT_RANK, dtpb + (size_t)i * D_INNER, dtb);

        scan_kernel<<<D_INNER / 16, 256, 0, stream>>>(
            xconv, dtb, xdbl, xz,
            alog + (size_t)i * D_INNER * D_STATE, Dw + (size_t)i * D_INNER, y);

        gemm_bt<MODE_ADD><<<dim3(8, 6), 256, 0, stream>>>(
            y, outw + (size_t)i * D_MODEL * D_INNER, hnxt,
            SEQ, D_MODEL, D_INNER, D_INNER, hcur);

        float* t = hcur; hcur = hnxt; hnxt = t;
    }

    ln_kernel<<<SEQ, 256, 0, stream>>>(hcur, lnfw, lnfb, hn);

    gemm_bt<MODE_PLAIN><<<dim3(8, (VOCAB + BN - 1) / BN), 256, 0, stream>>>(
        hn, emb, (float*)d_out, SEQ, VOCAB, D_MODEL, D_MODEL, nullptr);
}